// Round 1
// baseline (316.397 us; speedup 1.0000x reference)
//
#include <hip/hip_runtime.h>

// OrthogonalAddTSU: sequential scan over S steps, carry h:(B,H).
// Per step: cos = <h,s>/max(|h||s|,eps); h = clip(h + (s - h*cos)*m, -1, 1).
// B=64, H=1024, S=512. One wave per batch.
//
// Round-5 structure: LDS-transposed staging replaces scattered gathers.
//  - Old: 16B-per-row scattered loads, 64 lines/instr, L1-thrashed -> every
//    access a miss; ~3.2 cy per line-request dominated (175us, VALUBusy 3.2%).
//  - New: per 16-step tile, 64 coalesced buffer_load_dwordx4 (each = 16 full
//    64B lines, 4 lanes/line, consumed whole -> no thrash), reg ring ->
//    ds_write_b32 into LDS[t][row] (2x64KB ping-pong), compute reads 4x
//    contiguous ds_read_b128 per step (conflict-free).
//  - Pipeline: 8-slot chunk ring, vmcnt(12) (4 chunks in flight, issued 4
//    steps = ~1000cy ahead); sval read-ahead 1 step, lgkmcnt(0) at step top.
//  - All loop VMEM/LDS ops are volatile inline asm (compiler never emits its
//    own counted ops in the loop -> our vmcnt/lgkmcnt math is exact).
//  - SRSRC num_records = 2MB slab: tiles 30/31 keep issuing (OOB -> returns
//    0, written to the dead buffer) so one steady body serves all 32 tiles.
//  - Row ownership: lane l owns rows 4l+256m+i -> h load/store coalesced
//    dwordx4, LDS reads contiguous.
//  - Mask packed into one VGPR (bit i = mask[b][64i+lane]); per step one
//    readlane + scalar shift; m==0 steps skip compute (h already clipped),
//    t==0 m==0 clip handled in prologue.

#define NB 64
#define NH 1024
#define NS 512

typedef float v4f __attribute__((ext_vector_type(4)));
typedef int v4i __attribute__((ext_vector_type(4)));

template <int N> struct ic { static constexpr int value = N; };

template <int CTRL>
__device__ __forceinline__ float dpp_add(float x) {
  int s = __builtin_amdgcn_update_dpp(0, __builtin_bit_cast(int, x), CTRL, 0xf,
                                      0xf, true);
  return x + __builtin_bit_cast(float, s);
}

__device__ __forceinline__ float readlane_f(float v, int lane) {
  return __builtin_bit_cast(
      float, __builtin_amdgcn_readlane(__builtin_bit_cast(int, v), lane));
}

__device__ __forceinline__ void wave_sum3(float& a, float& b, float& c) {
  a = dpp_add<0x111>(a); b = dpp_add<0x111>(b); c = dpp_add<0x111>(c);
  a = dpp_add<0x112>(a); b = dpp_add<0x112>(b); c = dpp_add<0x112>(c);
  a = dpp_add<0x114>(a); b = dpp_add<0x114>(b); c = dpp_add<0x114>(c);
  a = dpp_add<0x118>(a); b = dpp_add<0x118>(b); c = dpp_add<0x118>(c);
  a = dpp_add<0x142>(a); b = dpp_add<0x142>(b); c = dpp_add<0x142>(c);
  a = dpp_add<0x143>(a); b = dpp_add<0x143>(b); c = dpp_add<0x143>(c);
  a = readlane_f(a, 63);
  b = readlane_f(b, 63);
  c = readlane_f(c, 63);
}

#define GLD4(dst, p, OFFSTR)                                   \
  asm volatile("global_load_dwordx4 %0, %1, off" OFFSTR        \
               : "=v"(dst)                                     \
               : "v"(p))
#define GLD1(dst, p)                                           \
  asm volatile("global_load_dword %0, %1, off" : "=v"(dst) : "v"(p))

template <int IMM>
__device__ __forceinline__ void dsr128(v4f& d, unsigned a) {
  asm volatile("ds_read_b128 %[d], %[a] offset:%[o]"
               : [d] "=v"(d)
               : [a] "v"(a), [o] "n"(IMM));
}
template <int IMM>
__device__ __forceinline__ void dsw32(unsigned a, float v) {
  asm volatile("ds_write_b32 %[a], %[v] offset:%[o]" ::[a] "v"(a), [v] "v"(v),
               [o] "n"(IMM));
}
__device__ __forceinline__ void bld4(v4f& d, unsigned voff, v4i srsrc,
                                     unsigned so) {
  asm volatile("buffer_load_dwordx4 %[d], %[vo], %[rs], %[so] offen"
               : [d] "=v"(d)
               : [vo] "v"(voff), [rs] "s"(srsrc), [so] "s"(so));
}

#define VMW12(rg)                                                          \
  asm volatile("s_waitcnt vmcnt(12)"                                       \
               : "+v"((rg)[0]), "+v"((rg)[1]), "+v"((rg)[2]), "+v"((rg)[3]))
#define LGK0(sv)                                                           \
  asm volatile("s_waitcnt lgkmcnt(0)"                                      \
               : "+v"((sv)[0]), "+v"((sv)[1]), "+v"((sv)[2]), "+v"((sv)[3]))

// Read step T (local) from LDS buffer base rb: 4 contiguous b128 per lane.
template <int T>
__device__ __forceinline__ void read_issue(unsigned rb, v4f (&sv)[4]) {
  dsr128<T * 4096 + 0>(sv[0], rb);
  dsr128<T * 4096 + 1024>(sv[1], rb);
  dsr128<T * 4096 + 2048>(sv[2], rb);
  dsr128<T * 4096 + 3072>(sv[3], rb);
}

// Write chunk S (load instrs k=4S..4S+3) into LDS[t][row] at base wb.
// Lane l of instr k holds row 16k + (l>>2), steps 4*(l&3)+j.
// byte = (4q+j)*4096 + row*4 = wb_lane + j*4096 + 64k.
template <int S>
__device__ __forceinline__ void stage_write(unsigned wb, v4f (&rg)[4]) {
#define DSWUJ(u, j) dsw32<(j) * 4096 + 256 * S + 64 * (u)>(wb, rg[u][j])
  DSWUJ(0, 0); DSWUJ(0, 1); DSWUJ(0, 2); DSWUJ(0, 3);
  DSWUJ(1, 0); DSWUJ(1, 1); DSWUJ(1, 2); DSWUJ(1, 3);
  DSWUJ(2, 0); DSWUJ(2, 1); DSWUJ(2, 2); DSWUJ(2, 3);
  DSWUJ(3, 0); DSWUJ(3, 1); DSWUJ(3, 2); DSWUJ(3, 3);
#undef DSWUJ
}

__device__ __forceinline__ void stage_load(v4f (&rg)[4], unsigned voff,
                                           v4i srsrc, unsigned& so) {
  bld4(rg[0], voff, srsrc, so); so += 32768u;
  bld4(rg[1], voff, srsrc, so); so += 32768u;
  bld4(rg[2], voff, srsrc, so); so += 32768u;
  bld4(rg[3], voff, srsrc, so); so += 32768u;
}

__device__ __forceinline__ void compute_step(float (&h)[16],
                                             const v4f (&sv)[4]) {
  float d0 = 0.f, d1 = 0.f, d2 = 0.f, d3 = 0.f;
  float e0 = 0.f, e1 = 0.f, e2 = 0.f, e3 = 0.f;
  float f0 = 0.f, f1 = 0.f, f2 = 0.f, f3 = 0.f;
#pragma unroll
  for (int m = 0; m < 4; ++m) {
    const float s0 = sv[m][0], s1 = sv[m][1], s2 = sv[m][2], s3 = sv[m][3];
    d0 = fmaf(h[4 * m + 0], s0, d0);
    e0 = fmaf(h[4 * m + 0], h[4 * m + 0], e0);
    f0 = fmaf(s0, s0, f0);
    d1 = fmaf(h[4 * m + 1], s1, d1);
    e1 = fmaf(h[4 * m + 1], h[4 * m + 1], e1);
    f1 = fmaf(s1, s1, f1);
    d2 = fmaf(h[4 * m + 2], s2, d2);
    e2 = fmaf(h[4 * m + 2], h[4 * m + 2], e2);
    f2 = fmaf(s2, s2, f2);
    d3 = fmaf(h[4 * m + 3], s3, d3);
    e3 = fmaf(h[4 * m + 3], h[4 * m + 3], e3);
    f3 = fmaf(s3, s3, f3);
  }
  float dot = (d0 + d1) + (d2 + d3);
  float hh = (e0 + e1) + (e2 + e3);
  float ss = (f0 + f1) + (f2 + f3);
  wave_sum3(dot, hh, ss);
  const float p = fmaxf(hh * ss, 1e-16f);  // denom^2, eps=1e-8
  const float c = dot * __builtin_amdgcn_rsqf(p);
  const float a = 1.0f - c;  // m==1: h_new = clip(h*(1-c) + s)
#pragma unroll
  for (int m = 0; m < 4; ++m) {
    h[4 * m + 0] =
        __builtin_amdgcn_fmed3f(fmaf(h[4 * m + 0], a, sv[m][0]), -1.0f, 1.0f);
    h[4 * m + 1] =
        __builtin_amdgcn_fmed3f(fmaf(h[4 * m + 1], a, sv[m][1]), -1.0f, 1.0f);
    h[4 * m + 2] =
        __builtin_amdgcn_fmed3f(fmaf(h[4 * m + 2], a, sv[m][2]), -1.0f, 1.0f);
    h[4 * m + 3] =
        __builtin_amdgcn_fmed3f(fmaf(h[4 * m + 3], a, sv[m][3]), -1.0f, 1.0f);
  }
}

__global__ __launch_bounds__(64, 1) void otsu_scan_kernel(
    const float* __restrict__ tree,   // (B,H)
    const float* __restrict__ seq,    // (B,H,S)
    const float* __restrict__ mask,   // (B,S)
    float* __restrict__ out) {        // (B,H)
  __shared__ float lds[2 * 16 * 1024];  // 128 KiB: 2 x [16 steps][1024 rows]
  const int b = blockIdx.x;
  const int l = threadIdx.x;  // 0..63

  // --- h: lane owns rows 4l+256m+i -> 4 coalesced dwordx4 ---
  const float* hrow = tree + b * NH + 4 * l;
  v4f hv[4];
  GLD4(hv[0], hrow, "");
  GLD4(hv[1], hrow, " offset:1024");
  GLD4(hv[2], hrow, " offset:2048");
  GLD4(hv[3], hrow, " offset:3072");
  float m8[8];
  {
    const float* mp = mask + b * NS + l;
    GLD1(m8[0], mp);
    GLD1(m8[1], mp + 64);
    GLD1(m8[2], mp + 128);
    GLD1(m8[3], mp + 192);
    GLD1(m8[4], mp + 256);
    GLD1(m8[5], mp + 320);
    GLD1(m8[6], mp + 384);
    GLD1(m8[7], mp + 448);
  }
  asm volatile("s_waitcnt vmcnt(0)"
               : "+v"(hv[0]), "+v"(hv[1]), "+v"(hv[2]), "+v"(hv[3]),
                 "+v"(m8[0]), "+v"(m8[1]), "+v"(m8[2]), "+v"(m8[3]),
                 "+v"(m8[4]), "+v"(m8[5]), "+v"(m8[6]), "+v"(m8[7]));

  float h[16];
#pragma unroll
  for (int m = 0; m < 4; ++m) {
    h[4 * m + 0] = hv[m][0];
    h[4 * m + 1] = hv[m][1];
    h[4 * m + 2] = hv[m][2];
    h[4 * m + 3] = hv[m][3];
  }

  // pack mask: bit i of lane l = (mask[b][64i+l] != 0)
  unsigned mbits = 0u;
#pragma unroll
  for (int i = 0; i < 8; ++i)
    if (m8[i] != 0.0f) mbits |= (1u << i);

  // t==0, m==0: clip still applies (handled once here; loop skips m==0)
  if (!(__builtin_amdgcn_readlane((int)mbits, 0) & 1)) {
#pragma unroll
    for (int i = 0; i < 16; ++i)
      h[i] = __builtin_amdgcn_fmed3f(h[i], -1.0f, 1.0f);
  }

  // --- addressing ---
  v4i srsrc;
  {
    const unsigned long long base =
        (unsigned long long)(seq + (size_t)b * NH * NS);
    srsrc[0] = (int)(unsigned)(base & 0xffffffffull);
    srsrc[1] = (int)(unsigned)(base >> 32);
    srsrc[2] = NH * NS * 4;  // num_records: OOB prefetch -> returns 0
    srsrc[3] = 0x00020000;
  }
  // stage instr k: lane l -> row 16k+(l>>2), 16B = steps 4*(l&3)..+3
  const unsigned voff = (unsigned)((l >> 2) * 2048 + (l & 3) * 16);
  const unsigned lb = (unsigned)(unsigned long long)(&lds[0]);
  const unsigned rb0 = lb + 16u * (unsigned)l;                       // reads
  const unsigned wb0 = lb + (unsigned)((l & 3) * 16384 + (l >> 2) * 4);
  unsigned so = 0u;

  v4f ring[8][4];   // 8-slot chunk ring (4 in flight, 4-step WAR distance)
  v4f sval[2][4];   // per-step s values, read-ahead double buffer

  // --- prologue: stage tile 0 fully, prime chunks 0..3 of tile 1 ---
  stage_load(ring[0], voff, srsrc, so);
  stage_load(ring[1], voff, srsrc, so);
  stage_load(ring[2], voff, srsrc, so);
  stage_load(ring[3], voff, srsrc, so);
#define PSTEP(v)                                              \
  do {                                                        \
    VMW12(ring[(v) & 7]);                                     \
    stage_write<(v)>(wb0, ring[(v) & 7]);                     \
    stage_load(ring[((v) + 4) & 7], voff, srsrc, so);         \
    if ((v) == 11) so -= 2097088u; /* wrap to next tile */    \
  } while (0)
  PSTEP(0);  PSTEP(1);  PSTEP(2);  PSTEP(3);
  PSTEP(4);  PSTEP(5);  PSTEP(6);  PSTEP(7);
  PSTEP(8);  PSTEP(9);  PSTEP(10); PSTEP(11);
  PSTEP(12); PSTEP(13); PSTEP(14); PSTEP(15);
#undef PSTEP

  read_issue<0>(rb0, sval[0]);  // step 0 of tile 0

  unsigned rb_cur = rb0;             // tile g reads buf g&1
  unsigned wb_cur = wb0 ^ 0x10000u;  // tile g writes buf (g+1)&1

#pragma unroll 1
  for (int g = 0; g < 32; ++g) {
    const int lbase = (16 * g) & 63;  // lane of step (16g) in its m8 word
    const int msh = g >> 2;           // bit index = t>>6
    auto step = [&](auto sc) {
      constexpr int S = decltype(sc)::value;
      LGK0(sval[S & 1]);  // sval ready (issued a full step ago)
      if constexpr (S < 15) read_issue<S + 1>(rb_cur, sval[(S + 1) & 1]);
      const unsigned mw =
          (unsigned)__builtin_amdgcn_readlane((int)mbits, lbase + S);
      if ((mw >> msh) & 1u) compute_step(h, sval[S & 1]);
      // staging: chunk S of next tile (loaded 4 steps ago) -> LDS; issue +4
      VMW12(ring[S & 7]);
      stage_write<S>(wb_cur, ring[S & 7]);
      stage_load(ring[(S + 4) & 7], voff, srsrc, so);
      if constexpr (S == 11) { so -= 2097088u; }
      // cross-tile read-ahead AFTER chunk-15 write (same-wave DS is in-order)
      if constexpr (S == 15) { read_issue<0>(rb_cur ^ 0x10000u, sval[0]); }
    };
    step(ic<0>{});  step(ic<1>{});  step(ic<2>{});  step(ic<3>{});
    step(ic<4>{});  step(ic<5>{});  step(ic<6>{});  step(ic<7>{});
    step(ic<8>{});  step(ic<9>{});  step(ic<10>{}); step(ic<11>{});
    step(ic<12>{}); step(ic<13>{}); step(ic<14>{}); step(ic<15>{});
    rb_cur ^= 0x10000u;
    wb_cur ^= 0x10000u;
  }

  // drain outstanding asm ops (OOB prefetches + last reads) before endpgm
  asm volatile("s_waitcnt vmcnt(0) lgkmcnt(0)" ::: "memory");

  // --- write final h (coalesced dwordx4) ---
  float* orow = out + b * NH + 4 * l;
#pragma unroll
  for (int m = 0; m < 4; ++m) {
    float4 v;
    v.x = h[4 * m + 0];
    v.y = h[4 * m + 1];
    v.z = h[4 * m + 2];
    v.w = h[4 * m + 3];
    *(float4*)(orow + 256 * m) = v;
  }
}

extern "C" void kernel_launch(void* const* d_in, const int* in_sizes, int n_in,
                              void* d_out, int out_size, void* d_ws,
                              size_t ws_size, hipStream_t stream) {
  const float* tree = (const float*)d_in[0];  // (64,1024)
  const float* seq = (const float*)d_in[1];   // (64,1024,512)
  const float* mask = (const float*)d_in[2];  // (64,512)
  float* out = (float*)d_out;                 // (64,1024)
  otsu_scan_kernel<<<dim3(NB), dim3(64), 0, stream>>>(tree, seq, mask, out);
}

// Round 4
// 310.690 us; speedup vs baseline: 1.0184x; 1.0184x over previous
//
#include <hip/hip_runtime.h>

// OrthogonalAddTSU: sequential scan over S steps, carry h:(B,H).
// Per step: cos = <h,s>/max(|h||s|,eps); h = clip(h + (s - h*cos)*m, -1, 1).
// B=64, H=1024, S=512.
//
// Round-8 = round-6/7 design, load encoding + barrier race fixed.
//  - r6/r7 failed to ASSEMBLE: "s" constraints (SRSRC / 64-bit saddr) on
//    values derived from w=tid>>6 -> divergence analysis keeps them in
//    VGPRs -> invalid operand. Fix: per-lane 64-bit pointer + the
//    "global_load_dwordx4 vdst, v[a:a+1], off" form (compiled in r4/r5).
//    Chunk advance = pointer += 8192 floats (2 VALU/step, noise).
//  - RACE FIX vs r6 plan: s_barrier now UNCONDITIONAL every step. With
//    active-only barriers, 3 consecutive masked steps (P~1e-3/pos, ~30
//    expected over the problem) would let a fast wave rewrite a 4-slot
//    partial slot before a slow wave's broadcast reads complete.
//  - Design: 4 waves per batch (256 threads). Wave w owns h[256w+4l..+3]
//    (one v4f/lane) and stages rows 256w..255 itself -> tile staging has
//    NO cross-wave dependency (each wave reads only rows it wrote; same-
//    wave DS is in-order). Only cross-wave traffic: 48B partial buffer.
//  - Per step per wave: 1 global load, 4 ds_write_b32, 1 ds_read_b128
//    (sval prefetch), 15 partial FMA, 18-DPP wave reduce, lane63 writes
//    {dot,hh,ss} to slot (S&3), lgkmcnt(0)+s_barrier, 3 broadcast
//    ds_read_b128, lgkmcnt(5), scalar cos math, 4 fma+med3 update.
//  - Staging pipeline: 8-slot single-load ring, vmcnt(3) => 4-step
//    issue-to-use distance (~1300cy). Tail (g>=30) wraps pointer to tile 0
//    (in-bounds garbage into the dead buffer, never consumed).
//  - All loop VMEM/LDS ops volatile inline asm (exact vmcnt/lgkmcnt math).
//  - Mask bit-packed; m==0 steps (block-uniform) skip compute+reads;
//    t==0 m==0 clip in prologue.

#define NB 64
#define NH 1024
#define NS 512

typedef float v4f __attribute__((ext_vector_type(4)));

template <int N> struct ic { static constexpr int value = N; };

template <int CTRL>
__device__ __forceinline__ float dpp_add(float x) {
  int s = __builtin_amdgcn_update_dpp(0, __builtin_bit_cast(int, x), CTRL, 0xf,
                                      0xf, true);
  return x + __builtin_bit_cast(float, s);
}

// 3 interleaved 6-stage butterflies; lane 63 ends with the full 64-lane sum.
__device__ __forceinline__ void wave_red3_to63(float& a, float& b, float& c) {
  a = dpp_add<0x111>(a); b = dpp_add<0x111>(b); c = dpp_add<0x111>(c);
  a = dpp_add<0x112>(a); b = dpp_add<0x112>(b); c = dpp_add<0x112>(c);
  a = dpp_add<0x114>(a); b = dpp_add<0x114>(b); c = dpp_add<0x114>(c);
  a = dpp_add<0x118>(a); b = dpp_add<0x118>(b); c = dpp_add<0x118>(c);
  a = dpp_add<0x142>(a); b = dpp_add<0x142>(b); c = dpp_add<0x142>(c);
  a = dpp_add<0x143>(a); b = dpp_add<0x143>(b); c = dpp_add<0x143>(c);
}

#define GLD4(dst, p) \
  asm volatile("global_load_dwordx4 %0, %1, off" : "=v"(dst) : "v"(p))
#define GLD1(dst, p) \
  asm volatile("global_load_dword %0, %1, off" : "=v"(dst) : "v"(p))

template <int IMM>
__device__ __forceinline__ void dsr128(v4f& d, unsigned a) {
  asm volatile("ds_read_b128 %[d], %[a] offset:%[o]"
               : [d] "=v"(d)
               : [a] "v"(a), [o] "n"(IMM));
}
template <int IMM>
__device__ __forceinline__ void dsw32(unsigned a, float v) {
  asm volatile("ds_write_b32 %[a], %[v] offset:%[o]" ::[a] "v"(a), [v] "v"(v),
               [o] "n"(IMM));
}

#define VMW3(r) asm volatile("s_waitcnt vmcnt(3)" : "+v"(r))
#define LGK0SV(sv) asm volatile("s_waitcnt lgkmcnt(0)" : "+v"(sv))
#define LGK5PR(p0, p1, p2)                  \
  asm volatile("s_waitcnt lgkmcnt(5)"       \
               : "+v"(p0), "+v"(p1), "+v"(p2))

// Write chunk S (rows 256w+16S..+15, all 16 steps of the tile) to LDS.
// Lane l holds row 256w+16S+(l>>2), steps 4(l&3)+j ->
// byte = 16384(l&3) + 4096j + 1024w + 64S + 4(l>>2) = wb + j*4096 + 64S.
template <int S>
__device__ __forceinline__ void stage_write(unsigned wb, v4f rg) {
  dsw32<0 * 4096 + 64 * S>(wb, rg[0]);
  dsw32<1 * 4096 + 64 * S>(wb, rg[1]);
  dsw32<2 * 4096 + 64 * S>(wb, rg[2]);
  dsw32<3 * 4096 + 64 * S>(wb, rg[3]);
}

__global__ __launch_bounds__(256, 1) void otsu_scan_kernel(
    const float* __restrict__ tree,   // (B,H)
    const float* __restrict__ seq,    // (B,H,S)
    const float* __restrict__ mask,   // (B,S)
    float* __restrict__ out) {        // (B,H)
  // 2 x [16 steps][1024 rows] tiles (128KB) + 4-slot partial buffer (256B)
  __shared__ float lds[2 * 16 * 1024 + 64];
  const int b = blockIdx.x;
  const int tid = threadIdx.x;
  const int w = tid >> 6;   // wave 0..3 (wave-uniform)
  const int l = tid & 63;   // lane

  // --- h: lane (w,l) owns h[256w + 4l .. +3] ---
  const float* hrow = tree + b * NH + 256 * w + 4 * l;
  v4f h;
  GLD4(h, hrow);
  float m8[8];
  {
    const float* mp = mask + b * NS + l;
    GLD1(m8[0], mp);
    GLD1(m8[1], mp + 64);
    GLD1(m8[2], mp + 128);
    GLD1(m8[3], mp + 192);
    GLD1(m8[4], mp + 256);
    GLD1(m8[5], mp + 320);
    GLD1(m8[6], mp + 384);
    GLD1(m8[7], mp + 448);
  }
  asm volatile("s_waitcnt vmcnt(0)"
               : "+v"(h), "+v"(m8[0]), "+v"(m8[1]), "+v"(m8[2]), "+v"(m8[3]),
                 "+v"(m8[4]), "+v"(m8[5]), "+v"(m8[6]), "+v"(m8[7]));

  // pack mask: bit i of lane l = (mask[b][64i+l] != 0)
  unsigned mbits = 0u;
#pragma unroll
  for (int i = 0; i < 8; ++i)
    if (m8[i] != 0.0f) mbits |= (1u << i);

  // t==0, m==0: clip still applies
  if (!(__builtin_amdgcn_readlane((int)mbits, 0) & 1)) {
#pragma unroll
    for (int i = 0; i < 4; ++i)
      h[i] = __builtin_amdgcn_fmed3f(h[i], -1.0f, 1.0f);
  }

  // --- addressing ---
  // per-lane load pointer: chunk k of tile g sits at
  //   sp0 + k*8192 + g*16 floats  (row (l>>2), step 4(l&3) inside the chunk)
  const float* sp0 = seq + (size_t)b * NH * NS + (size_t)w * 131072 +
                     (l >> 2) * 512 + (l & 3) * 4;
  const float* sp = sp0;
  const unsigned lb = (unsigned)(unsigned long long)(&lds[0]);
  unsigned rb = lb + 1024u * (unsigned)w + 16u * (unsigned)l;  // sval reads
  unsigned wbase =
      lb + 16384u * (unsigned)(l & 3) + 1024u * (unsigned)w +
      4u * (unsigned)(l >> 2);
  const unsigned vp = lb + 131072u + 4u * (unsigned)w;  // partial write (l63)
  const unsigned pb = lb + 131072u;                     // partial read base

  v4f ring[8];
  v4f sval[2];

  // --- prologue: stage tile 0 into buf0, prime tile-1 chunks 0..3 ---
  GLD4(ring[0], sp); sp += 8192;
  GLD4(ring[1], sp); sp += 8192;
  GLD4(ring[2], sp); sp += 8192;
  GLD4(ring[3], sp); sp += 8192;
#define PCH(c)                                              \
  do {                                                      \
    VMW3(ring[(c) & 7]);                                    \
    stage_write<(c)>(wbase, ring[(c) & 7]);                 \
    if ((c) == 12) sp -= 131056; /* wrap to next tile */    \
    GLD4(ring[((c) + 4) & 7], sp);                          \
    sp += 8192;                                             \
  } while (0)
  PCH(0);  PCH(1);  PCH(2);  PCH(3);
  PCH(4);  PCH(5);  PCH(6);  PCH(7);
  PCH(8);  PCH(9);  PCH(10); PCH(11);
  PCH(12); PCH(13); PCH(14); PCH(15);
#undef PCH

  dsr128<0>(sval[0], rb);  // step 0 of tile 0 (after own writes; DS in-order)

  unsigned wb = wbase ^ 0x10000u;  // tile g writes buf (g+1)&1

#pragma unroll 1
  for (int g = 0; g < 32; ++g) {
    const int lbase = (16 * g) & 63;
    const int msh = g >> 2;
    auto step = [&](auto sc) {
      constexpr int S = decltype(sc)::value;
      LGK0SV(sval[S & 1]);  // sval ready (prefetched last step; DS in-order)
      const unsigned mw =
          (unsigned)__builtin_amdgcn_readlane((int)mbits, lbase + S);
      const bool act = (mw >> msh) & 1u;  // block-uniform
      v4f pr0, pr1, pr2;
      if (act) {
        const v4f s = sval[S & 1];
        float pd0 = h[0] * s[0]; pd0 = fmaf(h[1], s[1], pd0);
        float pd1 = h[2] * s[2]; pd1 = fmaf(h[3], s[3], pd1);
        float ph0 = h[0] * h[0]; ph0 = fmaf(h[1], h[1], ph0);
        float ph1 = h[2] * h[2]; ph1 = fmaf(h[3], h[3], ph1);
        float ps0 = s[0] * s[0]; ps0 = fmaf(s[1], s[1], ps0);
        float ps1 = s[2] * s[2]; ps1 = fmaf(s[3], s[3], ps1);
        float pd = pd0 + pd1, ph = ph0 + ph1, ps = ps0 + ps1;
        wave_red3_to63(pd, ph, ps);
        if (l == 63) {
          dsw32<(S & 3) * 64 + 0>(vp, pd);
          dsw32<(S & 3) * 64 + 16>(vp, ph);
          dsw32<(S & 3) * 64 + 32>(vp, ps);
        }
        asm volatile("s_waitcnt lgkmcnt(0)" ::: "memory");
      }
      // UNCONDITIONAL barrier: keeps 4-slot partial rotation race-free even
      // across runs of masked-off steps (act is block-uniform).
      asm volatile("s_barrier" ::: "memory");
      if (act) {
        dsr128<(S & 3) * 64 + 0>(pr0, pb);   // broadcast reads
        dsr128<(S & 3) * 64 + 16>(pr1, pb);
        dsr128<(S & 3) * 64 + 32>(pr2, pb);
      }
      // --- staging (always): chunk S of tile g+1, issued 4 steps ago ---
      VMW3(ring[S & 7]);
      stage_write<S>(wb, ring[S & 7]);
      // wrap to next tile; g>=30 would run past the row end -> reuse tile-0
      // offsets (in-bounds garbage into the dead buffer, never consumed)
      if constexpr (S == 12) sp = (g < 30) ? sp - 131056 : sp0;
      GLD4(ring[(S + 4) & 7], sp);
      sp += 8192;
      // sval prefetch for next step (S==15: step 0 of next tile's buffer;
      // its chunk writes precede this read in the same wave -> in-order OK)
      if constexpr (S < 15) dsr128<(S + 1) * 4096>(sval[(S + 1) & 1], rb);
      else                  dsr128<0>(sval[0], rb ^ 0x10000u);
      if (act) {
        LGK5PR(pr0, pr1, pr2);  // 5 newer DS ops (4 writes + sval) may remain
        float dot = (pr0[0] + pr0[1]) + (pr0[2] + pr0[3]);
        float hh = (pr1[0] + pr1[1]) + (pr1[2] + pr1[3]);
        float ss = (pr2[0] + pr2[1]) + (pr2[2] + pr2[3]);
        const float p = fmaxf(hh * ss, 1e-16f);  // denom^2, eps=1e-8
        const float c = dot * __builtin_amdgcn_rsqf(p);
        const float a = 1.0f - c;  // h_new = clip(h*(1-c) + s)
        const v4f s = sval[S & 1];
#pragma unroll
        for (int i = 0; i < 4; ++i)
          h[i] = __builtin_amdgcn_fmed3f(fmaf(h[i], a, s[i]), -1.0f, 1.0f);
      }
    };
    step(ic<0>{});  step(ic<1>{});  step(ic<2>{});  step(ic<3>{});
    step(ic<4>{});  step(ic<5>{});  step(ic<6>{});  step(ic<7>{});
    step(ic<8>{});  step(ic<9>{});  step(ic<10>{}); step(ic<11>{});
    step(ic<12>{}); step(ic<13>{}); step(ic<14>{}); step(ic<15>{});
    rb ^= 0x10000u;
    wb ^= 0x10000u;
  }

  // drain outstanding asm ops (tail prefetches) before stores/endpgm
  asm volatile("s_waitcnt vmcnt(0) lgkmcnt(0)" ::: "memory");

  // --- write final h (coalesced dwordx4 per wave) ---
  float* orow = out + b * NH + 256 * w + 4 * l;
  float4 v;
  v.x = h[0];
  v.y = h[1];
  v.z = h[2];
  v.w = h[3];
  *(float4*)orow = v;
}

extern "C" void kernel_launch(void* const* d_in, const int* in_sizes, int n_in,
                              void* d_out, int out_size, void* d_ws,
                              size_t ws_size, hipStream_t stream) {
  const float* tree = (const float*)d_in[0];  // (64,1024)
  const float* seq = (const float*)d_in[1];   // (64,1024,512)
  const float* mask = (const float*)d_in[2];  // (64,512)
  float* out = (float*)d_out;                 // (64,1024)
  otsu_scan_kernel<<<dim3(NB), dim3(256), 0, stream>>>(tree, seq, mask, out);
}

// Round 6
// 270.369 us; speedup vs baseline: 1.1702x; 1.1491x over previous
//
#include <hip/hip_runtime.h>

// OrthogonalAddTSU: sequential scan over S steps, carry h:(B,H).
// Per step: cos = <h,s>/max(|h||s|,eps); h = clip(h + (s - h*cos)*m, -1, 1).
// B=64, H=1024, S=512.
//
// Round-10 = round-9 resubmitted verbatim (r9 bench = container infra
// failure, zero signal; design re-audited: barrier counts equal across
// role paths, all addresses in-bounds, full-window WAR distance).
//
// Design: producer/consumer wave specialization.
//  - r8 post-mortem: per-step cross-wave combine (DPP->write->lgkm(0)->
//    s_barrier->bcast read) costs ~550cy -- ate the entire 4-way-split win
//    (170us vs 176). Scan is latency-bound on the per-step serial chain.
//  - Wave 0 runs the WHOLE recurrence (no per-step barrier, r4-style
//    in-wave DPP reduce only); waves 1-3 are pure staging waves that
//    transpose 64KB tiles ([16 steps][1024 rows]) into 2x64KB LDS ping-pong.
//    ONE s_barrier per 16-step window (~35cy/step amortized).
//  - Consumer per step: lgkmcnt(0) on 4 prefetched ds_read_b128 (4KB of s),
//    packed-fp32 math: dot/hh/ss = 8 v_pk_mul/fma each + 3 pk_add tree,
//    3-chain DPP butterfly, readlane63, rsq, update = 8 pk_fma + 16 med3.
//    No staging, no address arith, no VMEM on the critical wave.
//  - Producers: per window, wave wp stages chunks c=3k+(wp-1) (22/21/21 of
//    64): 16-row coalesced global_load_dwordx4 each, vmcnt(0), 4 ds_write
//    _b32 each (4-way bank conflict, off critical path), lgkmcnt(0),
//    barrier. ~1300cy of work per ~4800cy window.
//  - Sync: barrier at end of every window g (33 total, equal count on both
//    wave-uniform paths -- legal divergent s_barrier). Producers write buf
//    (g+1)&1 during window g; consumer reads buf g&1; WAR distance = full
//    window.
//  - All VMEM/LDS in volatile inline asm; pk math in pure (schedulable)
//    inline asm. v_pk_fma_f32/v_pk_add_f32 are VOP3P (gfx90a+).
//  - Mask bit-packed in consumer; m==0 steps skip math (h already clipped);
//    t==0 m==0 clip in prologue.

#define NB 64
#define NH 1024
#define NS 512

typedef float v4f __attribute__((ext_vector_type(4)));
typedef float v2f __attribute__((ext_vector_type(2)));

template <int N> struct ic { static constexpr int value = N; };

template <int CTRL>
__device__ __forceinline__ float dpp_add(float x) {
  int s = __builtin_amdgcn_update_dpp(0, __builtin_bit_cast(int, x), CTRL, 0xf,
                                      0xf, true);
  return x + __builtin_bit_cast(float, s);
}

__device__ __forceinline__ float readlane_f(float v, int lane) {
  return __builtin_bit_cast(
      float, __builtin_amdgcn_readlane(__builtin_bit_cast(int, v), lane));
}

// 3 interleaved 6-stage butterflies; then broadcast lane63's totals.
__device__ __forceinline__ void wave_red3(float& a, float& b, float& c) {
  a = dpp_add<0x111>(a); b = dpp_add<0x111>(b); c = dpp_add<0x111>(c);
  a = dpp_add<0x112>(a); b = dpp_add<0x112>(b); c = dpp_add<0x112>(c);
  a = dpp_add<0x114>(a); b = dpp_add<0x114>(b); c = dpp_add<0x114>(c);
  a = dpp_add<0x118>(a); b = dpp_add<0x118>(b); c = dpp_add<0x118>(c);
  a = dpp_add<0x142>(a); b = dpp_add<0x142>(b); c = dpp_add<0x142>(c);
  a = dpp_add<0x143>(a); b = dpp_add<0x143>(b); c = dpp_add<0x143>(c);
  a = readlane_f(a, 63);
  b = readlane_f(b, 63);
  c = readlane_f(c, 63);
}

#define GLD4(dst, p) \
  asm volatile("global_load_dwordx4 %0, %1, off" : "=v"(dst) : "v"(p))
#define GLD1(dst, p) \
  asm volatile("global_load_dword %0, %1, off" : "=v"(dst) : "v"(p))

template <int IMM>
__device__ __forceinline__ void dsr128(v4f& d, unsigned a) {
  asm volatile("ds_read_b128 %[d], %[a] offset:%[o]"
               : [d] "=v"(d)
               : [a] "v"(a), [o] "n"(IMM));
}
template <int IMM>
__device__ __forceinline__ void dsw32(unsigned a, float v) {
  asm volatile("ds_write_b32 %[a], %[v] offset:%[o]" ::[a] "v"(a), [v] "v"(v),
               [o] "n"(IMM));
}

// Packed fp32 math (pure: compiler may schedule freely; real dataflow).
__device__ __forceinline__ v2f pk_fma(v2f a, v2f b, v2f c) {
  v2f d;
  asm("v_pk_fma_f32 %0, %1, %2, %3" : "=v"(d) : "v"(a), "v"(b), "v"(c));
  return d;
}
__device__ __forceinline__ v2f pk_mul(v2f a, v2f b) {
  v2f d;
  asm("v_pk_mul_f32 %0, %1, %2" : "=v"(d) : "v"(a), "v"(b));
  return d;
}
__device__ __forceinline__ v2f pk_add(v2f a, v2f b) {
  v2f d;
  asm("v_pk_add_f32 %0, %1, %2" : "=v"(d) : "v"(a), "v"(b));
  return d;
}

#define LGK0SV(s0, s1, s2, s3)                                       \
  asm volatile("s_waitcnt lgkmcnt(0)"                                \
               : "+v"(s0), "+v"(s1), "+v"(s2), "+v"(s3))

__global__ __launch_bounds__(256, 1) void otsu_scan_kernel(
    const float* __restrict__ tree,   // (B,H)
    const float* __restrict__ seq,    // (B,H,S)
    const float* __restrict__ mask,   // (B,S)
    float* __restrict__ out) {        // (B,H)
  __shared__ float lds[2 * 16 * 1024];  // 2 x [16 steps][1024 rows] = 128KiB
  const int b = blockIdx.x;
  const int tid = threadIdx.x;
  const int w = tid >> 6;   // wave 0..3 (wave-uniform)
  const int l = tid & 63;   // lane
  const unsigned lb = (unsigned)(unsigned long long)(&lds[0]);

  if (w == 0) {
    // ============================ CONSUMER ============================
    // lane l owns h[4l + 256m + {0..3}], m=0..3 -> 8 float2 pairs.
    const float* hrow = tree + b * NH + 4 * l;
    v4f hv0, hv1, hv2, hv3;
    GLD4(hv0, hrow);
    asm volatile("global_load_dwordx4 %0, %1, off offset:1024"
                 : "=v"(hv1) : "v"(hrow));
    asm volatile("global_load_dwordx4 %0, %1, off offset:2048"
                 : "=v"(hv2) : "v"(hrow));
    asm volatile("global_load_dwordx4 %0, %1, off offset:3072"
                 : "=v"(hv3) : "v"(hrow));
    float m8[8];
    {
      const float* mp = mask + b * NS + l;
      GLD1(m8[0], mp);
      GLD1(m8[1], mp + 64);
      GLD1(m8[2], mp + 128);
      GLD1(m8[3], mp + 192);
      GLD1(m8[4], mp + 256);
      GLD1(m8[5], mp + 320);
      GLD1(m8[6], mp + 384);
      GLD1(m8[7], mp + 448);
    }
    asm volatile("s_waitcnt vmcnt(0)"
                 : "+v"(hv0), "+v"(hv1), "+v"(hv2), "+v"(hv3), "+v"(m8[0]),
                   "+v"(m8[1]), "+v"(m8[2]), "+v"(m8[3]), "+v"(m8[4]),
                   "+v"(m8[5]), "+v"(m8[6]), "+v"(m8[7]));

    v2f h2[8];
    h2[0] = v2f{hv0[0], hv0[1]}; h2[1] = v2f{hv0[2], hv0[3]};
    h2[2] = v2f{hv1[0], hv1[1]}; h2[3] = v2f{hv1[2], hv1[3]};
    h2[4] = v2f{hv2[0], hv2[1]}; h2[5] = v2f{hv2[2], hv2[3]};
    h2[6] = v2f{hv3[0], hv3[1]}; h2[7] = v2f{hv3[2], hv3[3]};

    unsigned mbits = 0u;
#pragma unroll
    for (int i = 0; i < 8; ++i)
      if (m8[i] != 0.0f) mbits |= (1u << i);

    // t==0, m==0: clip still applies
    if (!(__builtin_amdgcn_readlane((int)mbits, 0) & 1)) {
#pragma unroll
      for (int p = 0; p < 8; ++p) {
        h2[p].x = __builtin_amdgcn_fmed3f(h2[p].x, -1.0f, 1.0f);
        h2[p].y = __builtin_amdgcn_fmed3f(h2[p].y, -1.0f, 1.0f);
      }
    }

    unsigned rb = lb + 16u * (unsigned)l;  // window g reads buf g&1
    v4f sval[2][4];

    asm volatile("s_barrier" ::: "memory");  // barrier #0: tile 0 staged

#pragma unroll 1
    for (int g = 0; g < 32; ++g) {
      const int lbase = (16 * g) & 63;
      const int msh = g >> 2;
      // step-0 reads (buffer just published by the barrier)
      dsr128<0 * 4096 + 0>(sval[0][0], rb);
      dsr128<0 * 4096 + 1024>(sval[0][1], rb);
      dsr128<0 * 4096 + 2048>(sval[0][2], rb);
      dsr128<0 * 4096 + 3072>(sval[0][3], rb);
      auto step = [&](auto sc) {
        constexpr int T = decltype(sc)::value;
        LGK0SV(sval[T & 1][0], sval[T & 1][1], sval[T & 1][2],
               sval[T & 1][3]);
        // prefetch next step's s (overlaps this step's math)
        if constexpr (T < 15) {
          dsr128<(T + 1) * 4096 + 0>(sval[(T + 1) & 1][0], rb);
          dsr128<(T + 1) * 4096 + 1024>(sval[(T + 1) & 1][1], rb);
          dsr128<(T + 1) * 4096 + 2048>(sval[(T + 1) & 1][2], rb);
          dsr128<(T + 1) * 4096 + 3072>(sval[(T + 1) & 1][3], rb);
        }
        const unsigned mw =
            (unsigned)__builtin_amdgcn_readlane((int)mbits, lbase + T);
        if ((mw >> msh) & 1u) {
          const v4f s0 = sval[T & 1][0], s1 = sval[T & 1][1],
                    s2 = sval[T & 1][2], s3 = sval[T & 1][3];
          v2f sp[8];
          sp[0] = v2f{s0[0], s0[1]}; sp[1] = v2f{s0[2], s0[3]};
          sp[2] = v2f{s1[0], s1[1]}; sp[3] = v2f{s1[2], s1[3]};
          sp[4] = v2f{s2[0], s2[1]}; sp[5] = v2f{s2[2], s2[3]};
          sp[6] = v2f{s3[0], s3[1]}; sp[7] = v2f{s3[2], s3[3]};
          v2f a0 = pk_mul(h2[0], sp[0]), a1 = pk_mul(h2[1], sp[1]);
          v2f a2 = pk_mul(h2[2], sp[2]), a3 = pk_mul(h2[3], sp[3]);
          v2f b0 = pk_mul(h2[0], h2[0]), b1 = pk_mul(h2[1], h2[1]);
          v2f b2 = pk_mul(h2[2], h2[2]), b3 = pk_mul(h2[3], h2[3]);
          v2f c0 = pk_mul(sp[0], sp[0]), c1 = pk_mul(sp[1], sp[1]);
          v2f c2 = pk_mul(sp[2], sp[2]), c3 = pk_mul(sp[3], sp[3]);
          a0 = pk_fma(h2[4], sp[4], a0); a1 = pk_fma(h2[5], sp[5], a1);
          a2 = pk_fma(h2[6], sp[6], a2); a3 = pk_fma(h2[7], sp[7], a3);
          b0 = pk_fma(h2[4], h2[4], b0); b1 = pk_fma(h2[5], h2[5], b1);
          b2 = pk_fma(h2[6], h2[6], b2); b3 = pk_fma(h2[7], h2[7], b3);
          c0 = pk_fma(sp[4], sp[4], c0); c1 = pk_fma(sp[5], sp[5], c1);
          c2 = pk_fma(sp[6], sp[6], c2); c3 = pk_fma(sp[7], sp[7], c3);
          v2f A = pk_add(pk_add(a0, a1), pk_add(a2, a3));
          v2f Bv = pk_add(pk_add(b0, b1), pk_add(b2, b3));
          v2f C = pk_add(pk_add(c0, c1), pk_add(c2, c3));
          float pd = A.x + A.y, ph = Bv.x + Bv.y, ps = C.x + C.y;
          wave_red3(pd, ph, ps);
          const float p = fmaxf(ph * ps, 1e-16f);  // denom^2, eps=1e-8
          const float cc = pd * __builtin_amdgcn_rsqf(p);
          const float aa = 1.0f - cc;  // h_new = clip(h*(1-c) + s)
          const v2f av = v2f{aa, aa};
#pragma unroll
          for (int q = 0; q < 8; ++q) {
            v2f t = pk_fma(h2[q], av, sp[q]);
            h2[q].x = __builtin_amdgcn_fmed3f(t.x, -1.0f, 1.0f);
            h2[q].y = __builtin_amdgcn_fmed3f(t.y, -1.0f, 1.0f);
          }
        }
      };
      step(ic<0>{});  step(ic<1>{});  step(ic<2>{});  step(ic<3>{});
      step(ic<4>{});  step(ic<5>{});  step(ic<6>{});  step(ic<7>{});
      step(ic<8>{});  step(ic<9>{});  step(ic<10>{}); step(ic<11>{});
      step(ic<12>{}); step(ic<13>{}); step(ic<14>{}); step(ic<15>{});
      rb ^= 0x10000u;
      asm volatile("s_barrier" ::: "memory");  // window g done
    }

    asm volatile("s_waitcnt vmcnt(0) lgkmcnt(0)" ::: "memory");
    float* orow = out + b * NH + 4 * l;
#pragma unroll
    for (int m = 0; m < 4; ++m) {
      float4 v;
      v.x = h2[2 * m].x;
      v.y = h2[2 * m].y;
      v.z = h2[2 * m + 1].x;
      v.w = h2[2 * m + 1].y;
      *(float4*)(orow + 256 * m) = v;
    }
  } else {
    // ============================ PRODUCERS ===========================
    // Wave wp=w stages chunks c = 3k + (w-1), k=0..21, c<64. Chunk c =
    // rows 16c..16c+15 x 16 steps. Lane l: row 16c+(l>>2), steps 4(l&3)+j.
    // LDS byte = bufsel + 16384(l&3) + j*4096 + 64c + 4(l>>2).
    const float* pbase = seq + (size_t)b * NH * NS + (l >> 2) * 512 +
                         (l & 3) * 4;
    const unsigned wpb =
        lb + 16384u * (unsigned)(l & 3) + 4u * (unsigned)(l >> 2);
    const int cb = w - 1;  // 0,1,2

    v4f ring[22];
    // stage(tile t, bufsel): all loads -> vmcnt(0) -> all writes -> lgkm(0)
#define STAGE(T_, BSEL_)                                                  \
    do {                                                                  \
      _Pragma("unroll") for (int k = 0; k < 22; ++k) {                    \
        const int c = 3 * k + cb;                                         \
        if (c < 64) {                                                     \
          const float* p_ = pbase + c * 8192 + (T_) * 16;                 \
          GLD4(ring[k], p_);                                              \
        }                                                                 \
      }                                                                   \
      asm volatile("s_waitcnt vmcnt(0)" ::: "memory");                    \
      _Pragma("unroll") for (int k = 0; k < 22; ++k) {                    \
        const int c = 3 * k + cb;                                         \
        if (c < 64) {                                                     \
          const unsigned a_ = wpb + (BSEL_) + 64u * (unsigned)c;          \
          dsw32<0>(a_, ring[k][0]);                                       \
          dsw32<4096>(a_, ring[k][1]);                                    \
          dsw32<8192>(a_, ring[k][2]);                                    \
          dsw32<12288>(a_, ring[k][3]);                                   \
        }                                                                 \
      }                                                                   \
      asm volatile("s_waitcnt lgkmcnt(0)" ::: "memory");                  \
    } while (0)

    STAGE(0, 0u);                            // tile 0 -> buf0
    asm volatile("s_barrier" ::: "memory");  // barrier #0

#pragma unroll 1
    for (int g = 0; g < 32; ++g) {
      if (g < 31) {
        const unsigned bsel = (unsigned)((g + 1) & 1) << 16;
        STAGE(g + 1, bsel);                  // tile g+1 -> buf (g+1)&1
      }
      asm volatile("s_barrier" ::: "memory");  // window g done
    }
#undef STAGE
  }
}

extern "C" void kernel_launch(void* const* d_in, const int* in_sizes, int n_in,
                              void* d_out, int out_size, void* d_ws,
                              size_t ws_size, hipStream_t stream) {
  const float* tree = (const float*)d_in[0];  // (64,1024)
  const float* seq = (const float*)d_in[1];   // (64,1024,512)
  const float* mask = (const float*)d_in[2];  // (64,512)
  float* out = (float*)d_out;                 // (64,1024)
  otsu_scan_kernel<<<dim3(NB), dim3(256), 0, stream>>>(tree, seq, mask, out);
}

// Round 9
// 266.046 us; speedup vs baseline: 1.1893x; 1.0162x over previous
//
#include <hip/hip_runtime.h>

// OrthogonalAddTSU: sequential scan over S steps, carry h:(B,H).
// Per step: cos = <h,s>/max(|h||s|,eps); h = clip(h + (s - h*cos)*m, -1, 1).
// B=64, H=1024, S=512.
//
// Round-13 = proven round-10 structure + 2 low-risk deltas (bisection).
//  - r11/r12 both "failed twice". r9 precedent says that error can be pure
//    infra; r11 likely hung (8B-aligned ds_read_b128); r12 re-audited clean
//    but shares r11's two novel subsystems (ds_swizzle butterfly, cross-
//    wave ssp partials). This round removes both and keeps only:
//    (1) LDS step stride 4096 -> 4112 B (=16*257, b128 alignment safe).
//        Producer write banks: (16(l&3)+(l>>2)) mod 32 -> exactly 2
//        lanes/bank = free wave64 minimum (was 4-way on 16 banks, 3.1M
//        conflict-cycles in r10 -- the prime consumer-stall suspect).
//        Consumer b128 reads remain contiguous/conflict-free.
//    (2) sval prefetch 2-deep, counted lgkmcnt(4) (T=15 drains to 0; no
//        DS op crosses a barrier).
//    |s|^2 stays in the consumer (as r10). If THIS fails twice too, it's
//    infra (r13 ~= r10 + address arithmetic) -> resubmit verbatim.
//  - Structure (r10, measured 131us): wave 0 = consumer, whole recurrence,
//    in-wave DPP reduce, no per-step barrier; waves 1-3 stage 65792B tiles
//    ([16 steps][stride 1028 floats]) double-buffered; 1 barrier per
//    16-step window (33 per path).
//  - All VMEM/LDS in volatile inline asm; pk math in pure inline asm.

#define NB 64
#define NH 1024
#define NS 512

#define STRF 1028              // step stride in floats (4112 B)
#define BUFF (16 * STRF)       // 16448 floats = 65792 B per tile buffer

typedef float v4f __attribute__((ext_vector_type(4)));
typedef float v2f __attribute__((ext_vector_type(2)));

template <int N> struct ic { static constexpr int value = N; };

template <int CTRL>
__device__ __forceinline__ float dpp_add(float x) {
  int s = __builtin_amdgcn_update_dpp(0, __builtin_bit_cast(int, x), CTRL, 0xf,
                                      0xf, true);
  return x + __builtin_bit_cast(float, s);
}

__device__ __forceinline__ float readlane_f(float v, int lane) {
  return __builtin_bit_cast(
      float, __builtin_amdgcn_readlane(__builtin_bit_cast(int, v), lane));
}

// 3 interleaved 6-stage butterflies; broadcast lane63 totals.
__device__ __forceinline__ void wave_red3(float& a, float& b, float& c) {
  a = dpp_add<0x111>(a); b = dpp_add<0x111>(b); c = dpp_add<0x111>(c);
  a = dpp_add<0x112>(a); b = dpp_add<0x112>(b); c = dpp_add<0x112>(c);
  a = dpp_add<0x114>(a); b = dpp_add<0x114>(b); c = dpp_add<0x114>(c);
  a = dpp_add<0x118>(a); b = dpp_add<0x118>(b); c = dpp_add<0x118>(c);
  a = dpp_add<0x142>(a); b = dpp_add<0x142>(b); c = dpp_add<0x142>(c);
  a = dpp_add<0x143>(a); b = dpp_add<0x143>(b); c = dpp_add<0x143>(c);
  a = readlane_f(a, 63);
  b = readlane_f(b, 63);
  c = readlane_f(c, 63);
}

#define GLD4(dst, p) \
  asm volatile("global_load_dwordx4 %0, %1, off" : "=v"(dst) : "v"(p))
#define GLD1(dst, p) \
  asm volatile("global_load_dword %0, %1, off" : "=v"(dst) : "v"(p))

template <int IMM>
__device__ __forceinline__ void dsr128(v4f& d, unsigned a) {
  asm volatile("ds_read_b128 %[d], %[a] offset:%[o]"
               : [d] "=v"(d)
               : [a] "v"(a), [o] "n"(IMM));
}
template <int IMM>
__device__ __forceinline__ void dsw32(unsigned a, float v) {
  asm volatile("ds_write_b32 %[a], %[v] offset:%[o]" ::[a] "v"(a), [v] "v"(v),
               [o] "n"(IMM));
}

// Packed fp32 math (pure: compiler may schedule freely; real dataflow).
__device__ __forceinline__ v2f pk_fma(v2f a, v2f b, v2f c) {
  v2f d;
  asm("v_pk_fma_f32 %0, %1, %2, %3" : "=v"(d) : "v"(a), "v"(b), "v"(c));
  return d;
}
__device__ __forceinline__ v2f pk_mul(v2f a, v2f b) {
  v2f d;
  asm("v_pk_mul_f32 %0, %1, %2" : "=v"(d) : "v"(a), "v"(b));
  return d;
}
__device__ __forceinline__ v2f pk_add(v2f a, v2f b) {
  v2f d;
  asm("v_pk_add_f32 %0, %1, %2" : "=v"(d) : "v"(a), "v"(b));
  return d;
}

#define LGK4SV(sv)                                                    \
  asm volatile("s_waitcnt lgkmcnt(4)"                                 \
               : "+v"((sv)[0]), "+v"((sv)[1]), "+v"((sv)[2]),         \
                 "+v"((sv)[3]))
#define LGK0SV(sv)                                                    \
  asm volatile("s_waitcnt lgkmcnt(0)"                                 \
               : "+v"((sv)[0]), "+v"((sv)[1]), "+v"((sv)[2]),         \
                 "+v"((sv)[3]))

__global__ __launch_bounds__(256, 1) void otsu_scan_kernel(
    const float* __restrict__ tree,   // (B,H)
    const float* __restrict__ seq,    // (B,H,S)
    const float* __restrict__ mask,   // (B,S)
    float* __restrict__ out) {        // (B,H)
  __shared__ float lds[2 * BUFF];  // 131584 B < 160 KiB
  const int b = blockIdx.x;
  const int tid = threadIdx.x;
  const int w = tid >> 6;   // wave 0..3 (wave-uniform)
  const int l = tid & 63;   // lane
  const unsigned lb = (unsigned)(unsigned long long)(&lds[0]);

  if (w == 0) {
    // ============================ CONSUMER ============================
    // lane l owns h[4l + 256m + {0..3}], m=0..3 -> 8 float2 pairs.
    const float* hrow = tree + b * NH + 4 * l;
    v4f hv0, hv1, hv2, hv3;
    GLD4(hv0, hrow);
    asm volatile("global_load_dwordx4 %0, %1, off offset:1024"
                 : "=v"(hv1) : "v"(hrow));
    asm volatile("global_load_dwordx4 %0, %1, off offset:2048"
                 : "=v"(hv2) : "v"(hrow));
    asm volatile("global_load_dwordx4 %0, %1, off offset:3072"
                 : "=v"(hv3) : "v"(hrow));
    float m8[8];
    {
      const float* mp = mask + b * NS + l;
      GLD1(m8[0], mp);
      GLD1(m8[1], mp + 64);
      GLD1(m8[2], mp + 128);
      GLD1(m8[3], mp + 192);
      GLD1(m8[4], mp + 256);
      GLD1(m8[5], mp + 320);
      GLD1(m8[6], mp + 384);
      GLD1(m8[7], mp + 448);
    }
    asm volatile("s_waitcnt vmcnt(0)"
                 : "+v"(hv0), "+v"(hv1), "+v"(hv2), "+v"(hv3), "+v"(m8[0]),
                   "+v"(m8[1]), "+v"(m8[2]), "+v"(m8[3]), "+v"(m8[4]),
                   "+v"(m8[5]), "+v"(m8[6]), "+v"(m8[7]));

    v2f h2[8];
    h2[0] = v2f{hv0[0], hv0[1]}; h2[1] = v2f{hv0[2], hv0[3]};
    h2[2] = v2f{hv1[0], hv1[1]}; h2[3] = v2f{hv1[2], hv1[3]};
    h2[4] = v2f{hv2[0], hv2[1]}; h2[5] = v2f{hv2[2], hv2[3]};
    h2[6] = v2f{hv3[0], hv3[1]}; h2[7] = v2f{hv3[2], hv3[3]};

    unsigned mbits = 0u;
#pragma unroll
    for (int i = 0; i < 8; ++i)
      if (m8[i] != 0.0f) mbits |= (1u << i);

    // t==0, m==0: clip still applies
    if (!(__builtin_amdgcn_readlane((int)mbits, 0) & 1)) {
#pragma unroll
      for (int p = 0; p < 8; ++p) {
        h2[p].x = __builtin_amdgcn_fmed3f(h2[p].x, -1.0f, 1.0f);
        h2[p].y = __builtin_amdgcn_fmed3f(h2[p].y, -1.0f, 1.0f);
      }
    }

    const unsigned rb0 = lb + 16u * (unsigned)l;
    v4f sval[3][4];

    asm volatile("s_barrier" ::: "memory");  // barrier #0: tile 0 staged

#pragma unroll 1
    for (int g = 0; g < 32; ++g) {
      const int lbase = (16 * g) & 63;
      const int msh = g >> 2;
      const unsigned rbuf = rb0 + ((g & 1) ? (unsigned)(BUFF * 4) : 0u);

      // --- window preamble: issue steps 0,1 (8 b128); wait step 0 ---
      dsr128<0 * 4112 + 0>(sval[0][0], rbuf);
      dsr128<0 * 4112 + 1024>(sval[0][1], rbuf);
      dsr128<0 * 4112 + 2048>(sval[0][2], rbuf);
      dsr128<0 * 4112 + 3072>(sval[0][3], rbuf);
      dsr128<1 * 4112 + 0>(sval[1][0], rbuf);
      dsr128<1 * 4112 + 1024>(sval[1][1], rbuf);
      dsr128<1 * 4112 + 2048>(sval[1][2], rbuf);
      dsr128<1 * 4112 + 3072>(sval[1][3], rbuf);
      LGK4SV(sval[0]);

      auto step = [&](auto sc) {
        constexpr int T = decltype(sc)::value;
        if constexpr (T >= 1 && T <= 14) LGK4SV(sval[T % 3]);
        else if constexpr (T == 15) LGK0SV(sval[0]);
        if constexpr (T <= 13) {  // prefetch step T+2 (2-deep)
          dsr128<(T + 2) * 4112 + 0>(sval[(T + 2) % 3][0], rbuf);
          dsr128<(T + 2) * 4112 + 1024>(sval[(T + 2) % 3][1], rbuf);
          dsr128<(T + 2) * 4112 + 2048>(sval[(T + 2) % 3][2], rbuf);
          dsr128<(T + 2) * 4112 + 3072>(sval[(T + 2) % 3][3], rbuf);
        }
        const unsigned mw =
            (unsigned)__builtin_amdgcn_readlane((int)mbits, lbase + T);
        if ((mw >> msh) & 1u) {
          const v4f s0 = sval[T % 3][0], s1 = sval[T % 3][1],
                    s2 = sval[T % 3][2], s3 = sval[T % 3][3];
          v2f sp[8];
          sp[0] = v2f{s0[0], s0[1]}; sp[1] = v2f{s0[2], s0[3]};
          sp[2] = v2f{s1[0], s1[1]}; sp[3] = v2f{s1[2], s1[3]};
          sp[4] = v2f{s2[0], s2[1]}; sp[5] = v2f{s2[2], s2[3]};
          sp[6] = v2f{s3[0], s3[1]}; sp[7] = v2f{s3[2], s3[3]};
          v2f a0 = pk_mul(h2[0], sp[0]), a1 = pk_mul(h2[1], sp[1]);
          v2f a2 = pk_mul(h2[2], sp[2]), a3 = pk_mul(h2[3], sp[3]);
          v2f b0 = pk_mul(h2[0], h2[0]), b1 = pk_mul(h2[1], h2[1]);
          v2f b2 = pk_mul(h2[2], h2[2]), b3 = pk_mul(h2[3], h2[3]);
          v2f c0 = pk_mul(sp[0], sp[0]), c1 = pk_mul(sp[1], sp[1]);
          v2f c2 = pk_mul(sp[2], sp[2]), c3 = pk_mul(sp[3], sp[3]);
          a0 = pk_fma(h2[4], sp[4], a0); a1 = pk_fma(h2[5], sp[5], a1);
          a2 = pk_fma(h2[6], sp[6], a2); a3 = pk_fma(h2[7], sp[7], a3);
          b0 = pk_fma(h2[4], h2[4], b0); b1 = pk_fma(h2[5], h2[5], b1);
          b2 = pk_fma(h2[6], h2[6], b2); b3 = pk_fma(h2[7], h2[7], b3);
          c0 = pk_fma(sp[4], sp[4], c0); c1 = pk_fma(sp[5], sp[5], c1);
          c2 = pk_fma(sp[6], sp[6], c2); c3 = pk_fma(sp[7], sp[7], c3);
          v2f A = pk_add(pk_add(a0, a1), pk_add(a2, a3));
          v2f Bv = pk_add(pk_add(b0, b1), pk_add(b2, b3));
          v2f C = pk_add(pk_add(c0, c1), pk_add(c2, c3));
          float pd = A.x + A.y, ph = Bv.x + Bv.y, ps = C.x + C.y;
          wave_red3(pd, ph, ps);
          const float p = fmaxf(ph * ps, 1e-16f);  // denom^2, eps=1e-8
          const float cc = pd * __builtin_amdgcn_rsqf(p);
          const float aa = 1.0f - cc;  // h_new = clip(h*(1-c) + s)
          const v2f av = v2f{aa, aa};
#pragma unroll
          for (int q = 0; q < 8; ++q) {
            v2f t = pk_fma(h2[q], av, sp[q]);
            h2[q].x = __builtin_amdgcn_fmed3f(t.x, -1.0f, 1.0f);
            h2[q].y = __builtin_amdgcn_fmed3f(t.y, -1.0f, 1.0f);
          }
        }
      };
      step(ic<0>{});  step(ic<1>{});  step(ic<2>{});  step(ic<3>{});
      step(ic<4>{});  step(ic<5>{});  step(ic<6>{});  step(ic<7>{});
      step(ic<8>{});  step(ic<9>{});  step(ic<10>{}); step(ic<11>{});
      step(ic<12>{}); step(ic<13>{}); step(ic<14>{}); step(ic<15>{});
      asm volatile("s_barrier" ::: "memory");  // window g done
    }

    asm volatile("s_waitcnt vmcnt(0) lgkmcnt(0)" ::: "memory");
    float* orow = out + b * NH + 4 * l;
#pragma unroll
    for (int m = 0; m < 4; ++m) {
      float4 v;
      v.x = h2[2 * m].x;
      v.y = h2[2 * m].y;
      v.z = h2[2 * m + 1].x;
      v.w = h2[2 * m + 1].y;
      *(float4*)(orow + 256 * m) = v;
    }
  } else {
    // ============================ PRODUCERS ===========================
    // Wave w stages chunks c = 3k + (w-1), k=0..21, c<64. Chunk c = rows
    // 16c..16c+15 x 16 steps. Lane l: row 16c+(l>>2), steps 4(l&3)+j.
    // LDS byte(step t,row r) = bsel + t*4112 + 4r ->
    //   wpb = 16448(l&3) + 4(l>>2); write j at wpb + j*4112 + 64c.
    // Banks: (16(l&3)+(l>>2)) mod 32 -> 2 lanes/bank (free wave64 minimum).
    const float* pbase = seq + (size_t)b * NH * NS + (l >> 2) * 512 +
                         (l & 3) * 4;
    const unsigned wpb =
        lb + 16448u * (unsigned)(l & 3) + 4u * (unsigned)(l >> 2);
    const int cb = w - 1;  // 0,1,2

    v4f ring[22];
    // stage(tile t, bufsel): all loads -> vmcnt(0) -> all writes -> lgkm(0)
#define STAGE(T_, BSEL_)                                                  \
    do {                                                                  \
      _Pragma("unroll") for (int k = 0; k < 22; ++k) {                    \
        const int c = 3 * k + cb;                                         \
        if (c < 64) {                                                     \
          const float* p_ = pbase + c * 8192 + (T_) * 16;                 \
          GLD4(ring[k], p_);                                              \
        }                                                                 \
      }                                                                   \
      asm volatile("s_waitcnt vmcnt(0)" ::: "memory");                    \
      _Pragma("unroll") for (int k = 0; k < 22; ++k) {                    \
        const int c = 3 * k + cb;                                         \
        if (c < 64) {                                                     \
          const unsigned a_ = wpb + (BSEL_) + 64u * (unsigned)c;          \
          dsw32<0 * 4112>(a_, ring[k][0]);                                \
          dsw32<1 * 4112>(a_, ring[k][1]);                                \
          dsw32<2 * 4112>(a_, ring[k][2]);                                \
          dsw32<3 * 4112>(a_, ring[k][3]);                                \
        }                                                                 \
      }                                                                   \
      asm volatile("s_waitcnt lgkmcnt(0)" ::: "memory");                  \
    } while (0)

    STAGE(0, 0u);                            // tile 0 -> buf0
    asm volatile("s_barrier" ::: "memory");  // barrier #0

#pragma unroll 1
    for (int g = 0; g < 32; ++g) {
      if (g < 31) {
        const unsigned bsel = ((g + 1) & 1) ? (unsigned)(BUFF * 4) : 0u;
        STAGE(g + 1, bsel);                  // tile g+1 -> buf (g+1)&1
      }
      asm volatile("s_barrier" ::: "memory");  // window g done
    }
#undef STAGE
  }
}

extern "C" void kernel_launch(void* const* d_in, const int* in_sizes, int n_in,
                              void* d_out, int out_size, void* d_ws,
                              size_t ws_size, hipStream_t stream) {
  const float* tree = (const float*)d_in[0];  // (64,1024)
  const float* seq = (const float*)d_in[1];   // (64,1024,512)
  const float* mask = (const float*)d_in[2];  // (64,512)
  float* out = (float*)d_out;                 // (64,1024)
  otsu_scan_kernel<<<dim3(NB), dim3(256), 0, stream>>>(tree, seq, mask, out);
}